// Round 16
// baseline (373.671 us; speedup 1.0000x reference)
//
#include <hip/hip_runtime.h>
#include <hip/hip_bf16.h>
#include <math.h>

#define HID   128
#define TPB   256      // 4 waves per block
#define UROWS 32       // rows per work unit (one wave-tile)
#define NBLK  768      // 3 blocks/CU co-resident

typedef __attribute__((ext_vector_type(8))) short        short8v;   // 8 bf16
typedef __attribute__((ext_vector_type(4))) float        f32x4;
typedef __attribute__((ext_vector_type(4))) unsigned int uint4v;

#define MFMA(a, b, c) __builtin_amdgcn_mfma_f32_16x16x32_bf16((a), (b), (c), 0, 0, 0)
#define SCHED_FENCE() __builtin_amdgcn_sched_barrier(0)
#define BC8(x) __builtin_bit_cast(short8v, x)

// Native packed f32->bf16 pair conversion (1 VALU inst).
__device__ __forceinline__ unsigned int pk2bf(float lo, float hi) {
    unsigned int r;
    asm("v_cvt_pk_bf16_f32 %0, %1, %2" : "=v"(r) : "v"(lo), "v"(hi));
    return r;
}
// bf16 round-trip (hi part of hi-lo split).
__device__ __forceinline__ float bfhi(float x) {
    unsigned int r;
    asm("v_cvt_pk_bf16_f32 %0, %1, %2" : "=v"(r) : "v"(0.f), "v"(x));
    return __builtin_bit_cast(float, r);
}
__device__ __forceinline__ f32x4 relu4(f32x4 v) {
    f32x4 r;
    r.x = fmaxf(v.x, 0.f); r.y = fmaxf(v.y, 0.f);
    r.z = fmaxf(v.z, 0.f); r.w = fmaxf(v.w, 0.f);
    return r;
}

__global__ __launch_bounds__(TPB, 2)
void stress_kernel(const float* __restrict__ F,
                   const float* __restrict__ W1, const float* __restrict__ b1,
                   const float* __restrict__ W2, const float* __restrict__ b2,
                   const float* __restrict__ W3, const float* __restrict__ b3,
                   float* __restrict__ out, unsigned int* __restrict__ cnt, int N)
{
    // ---- LDS (~46.6 KB -> 3 blocks/CU) ----
    __shared__ uint4v sA2[2048];   // 32 KB  W2^T A-frags, slot k = 4g+(b&3)+16*(2ks+(b>>2))
    __shared__ uint4v sA1[512];    //  8 KB  layer-1 A-frags (hi-lo W1 + b1 slots)
    __shared__ uint4v sA3[256];    //  4 KB  W3^T A-frags
    __shared__ f32x4  sY[128];     //  2 KB  per-wave y transpose
    __shared__ __align__(16) float sb2[HID];

    const int tid  = threadIdx.x;
    const int lane = tid & 63;
    const int wid  = tid >> 6;
    const int g    = lane >> 4;     // lane group 0..3
    const int lr   = lane & 15;

    // ---- one-time staging (identical to R15) ----
    for (int e = tid; e < 2048; e += TPB) {
        int l = e & 63, ks = (e >> 6) & 3, jt = e >> 8;
        int gg = l >> 4;
        int j  = (l & 15) + 16 * jt;
        #define K2(B) (4 * gg + ((B) & 3) + 16 * (2 * ks + ((B) >> 2)))
        uint4v v;
        v.x = pk2bf(W2[K2(0) * HID + j], W2[K2(1) * HID + j]);
        v.y = pk2bf(W2[K2(2) * HID + j], W2[K2(3) * HID + j]);
        v.z = pk2bf(W2[K2(4) * HID + j], W2[K2(5) * HID + j]);
        v.w = pk2bf(W2[K2(6) * HID + j], W2[K2(7) * HID + j]);
        #undef K2
        sA2[e] = v;
    }
    for (int e = tid; e < 512; e += TPB) {
        int l = e & 63, jt = e >> 6;
        int gg = l >> 4;
        int j  = (l & 15) + 16 * jt;
        float av[8];
        #pragma unroll
        for (int b = 0; b < 8; ++b) {
            int c = 8 * gg + b;
            float v;
            if      (c < 3)   v = W1[c * HID + j];
            else if (c < 6)   v = W1[(c - 3) * HID + j] - bfhi(W1[(c - 3) * HID + j]);
            else if (c < 9)   v = W1[(c - 6) * HID + j];
            else if (c == 9)  v = b1[j];
            else if (c == 10) v = b1[j] - bfhi(b1[j]);
            else              v = 0.f;
            av[b] = v;
        }
        uint4v v;
        v.x = pk2bf(av[0], av[1]); v.y = pk2bf(av[2], av[3]);
        v.z = pk2bf(av[4], av[5]); v.w = pk2bf(av[6], av[7]);
        sA1[e] = v;
    }
    for (int e = tid; e < 256; e += TPB) {
        int l = e & 63, ks2 = e >> 6;
        int gg = l >> 4, t = l & 15;
        float w[8];
        #pragma unroll
        for (int b = 0; b < 8; ++b) {
            int j = 4 * gg + (b & 3) + 16 * (2 * ks2 + (b >> 2));
            w[b] = (t < 4) ? W3[j * 4 + t] : 0.f;
        }
        uint4v v;
        v.x = pk2bf(w[0], w[1]); v.y = pk2bf(w[2], w[3]);
        v.z = pk2bf(w[4], w[5]); v.w = pk2bf(w[6], w[7]);
        sA3[e] = v;
    }
    for (int i = tid; i < HID; i += TPB) sb2[i] = b2[i];
    __syncthreads();

    const f32x4* pB2 = (const f32x4*)sb2;
    const f32x4  z4  = {0.f, 0.f, 0.f, 0.f};

    // b3 C-in fragment (only g==0 rows are real W3 rows)
    f32x4 b3v = z4;
    if (g == 0) b3v = *(const f32x4*)b3;

    const int nUnits  = (N + UROWS - 1) / UROWS;
    const int nStatic = (int)gridDim.x * 4;

    // static first unit per wave; prefetch its F rows
    int unit = (int)blockIdx.x * 4 + wid;
    f32x4 fv = z4;
    if (lane < 32 && unit < nUnits) {
        int n = unit * UROWS + lane;
        if (n < N) fv = ((const f32x4*)F)[n];
    }

    while (unit < nUnits) {
        // grab next dynamic unit EARLY (latency hides under KS0)
        unsigned int nd = 0;
        if (lane == 0) nd = atomicAdd(cnt, 1u);

        const int nbase = unit * UROWS;

        // ---- prologue: invariants + polar R via v_rsq ----
        const float fa = fv.x, fb = fv.y, fc = fv.z, fd = fv.w;
        float x0, x1, x2, R00, R01, R10, R11;
        {
            const float J   = fa * fd - fb * fc;
            const float ss  = fa * fa + fb * fb + fc * fc + fd * fd;
            const float sgn = (J >= 0.f) ? 1.f : -1.f;
            const float s   = fmaxf(ss + 2.f * fabsf(J), 1e-30f);
            float inv;
            asm("v_rsq_f32 %0, %1" : "=v"(inv) : "v"(s));
            const float r = s * inv;            // sqrt(s)
            x0 = r - 2.f; x1 = ss - 1.f; x2 = J - 1.f;
            R00 = (fa + sgn * fd) * inv; R01 = (fb - sgn * fc) * inv;
            R10 = (fc - sgn * fb) * inv; R11 = (fd + sgn * fa) * inv;
        }

        // ---- b2 acc-init reads + a1 frags (KS0 + KS1) + B1 frags ----
        const f32x4 ba0 = pB2[g +  0], bb0 = pB2[g +  4];
        const f32x4 ba1 = pB2[g +  8], bb1 = pB2[g + 12];
        const f32x4 ba2 = pB2[g + 16], bb2 = pB2[g + 20];
        const f32x4 ba3 = pB2[g + 24], bb3 = pB2[g + 28];
        short8v a1P_0 = BC8(sA1[0 * 64 + lane]), a1P_1 = BC8(sA1[1 * 64 + lane]);
        short8v a1Q_0 = BC8(sA1[2 * 64 + lane]), a1Q_1 = BC8(sA1[3 * 64 + lane]);
        short8v a3f_0, a3f_1, a3f_2, a3f_3;

        short8v b1f_0, b1f_1;
        #define B1BUILD(RT, DST) {                                                 \
            const float bx0 = __shfl(x0, (RT) * 16 + lr, 64);                      \
            const float bx1 = __shfl(x1, (RT) * 16 + lr, 64);                      \
            const float bx2 = __shfl(x2, (RT) * 16 + lr, 64);                      \
            const float xl0 = bx0 - bfhi(bx0);                                     \
            const float xl1 = bx1 - bfhi(bx1);                                     \
            const float xl2 = bx2 - bfhi(bx2);                                     \
            uint4v u;                                                              \
            u.x = (g == 0) ? pk2bf(bx0, bx1) : ((g == 1) ? pk2bf(xl2, 1.f) : 0u);  \
            u.y = (g == 0) ? pk2bf(bx2, bx0) : ((g == 1) ? pk2bf(1.f, 0.f) : 0u);  \
            u.z = (g == 0) ? pk2bf(bx1, bx2) : 0u;                                 \
            u.w = (g == 0) ? pk2bf(xl0, xl1) : 0u;                                 \
            DST = __builtin_bit_cast(short8v, u);                                  \
        }
        B1BUILD(0, b1f_0) B1BUILD(1, b1f_1)
        #undef B1BUILD

        // L1 for KS0 (lookahead seed)
        #define L1CALC(A0, A1, D00, D01, D10, D11)   \
            D00 = MFMA(A0, b1f_0, z4); D01 = MFMA(A0, b1f_1, z4); \
            D10 = MFMA(A1, b1f_0, z4); D11 = MFMA(A1, b1f_1, z4);
        f32x4 p00, p01, p10, p11, q00, q01, q10, q11;
        L1CALC(a1P_0, a1P_1, p00, p01, p10, p11)
        SCHED_FENCE();

        // ---- layer-2 accumulators, C-in = b2 fragment ----
        f32x4 acc_0_0 = ba0, acc_0_1 = ba0, acc_1_0 = bb0, acc_1_1 = bb0,
              acc_2_0 = ba1, acc_2_1 = ba1, acc_3_0 = bb1, acc_3_1 = bb1,
              acc_4_0 = ba2, acc_4_1 = ba2, acc_5_0 = bb2, acc_5_1 = bb2,
              acc_6_0 = ba3, acc_6_1 = ba3, acc_7_0 = bb3, acc_7_1 = bb3;

        short8v bf_0, bf_1;
        #define PACK2(H00, H01, H10, H11) {                                       \
            const f32x4 ra = relu4(H00), rb = relu4(H10);                         \
            const f32x4 rc = relu4(H01), rd = relu4(H11);                         \
            uint4v u0, u1;                                                        \
            u0.x = pk2bf(ra.x, ra.y); u0.y = pk2bf(ra.z, ra.w);                   \
            u0.z = pk2bf(rb.x, rb.y); u0.w = pk2bf(rb.z, rb.w);                   \
            u1.x = pk2bf(rc.x, rc.y); u1.y = pk2bf(rc.z, rc.w);                   \
            u1.z = pk2bf(rd.x, rd.y); u1.w = pk2bf(rd.z, rd.w);                   \
            bf_0 = BC8(u0); bf_1 = BC8(u1);                                       \
        }
        #define STEP(JT, RT) acc_##JT##_##RT = MFMA(af_##JT, bf_##RT, acc_##JT##_##RT)
        // KSBLOCK: {af reads | pack h(KS) | L1(KS+1) from pre-read a1 | a1/a3f
        //           prefetch | 16 L2 MFMA}; fence caps live ranges.
        #define KSBLOCK(KS, H00, H01, H10, H11, NEXTPART) {                       \
            const short8v af_0 = BC8(sA2[(0*4+(KS))*64+lane]);                    \
            const short8v af_1 = BC8(sA2[(1*4+(KS))*64+lane]);                    \
            const short8v af_2 = BC8(sA2[(2*4+(KS))*64+lane]);                    \
            const short8v af_3 = BC8(sA2[(3*4+(KS))*64+lane]);                    \
            const short8v af_4 = BC8(sA2[(4*4+(KS))*64+lane]);                    \
            const short8v af_5 = BC8(sA2[(5*4+(KS))*64+lane]);                    \
            const short8v af_6 = BC8(sA2[(6*4+(KS))*64+lane]);                    \
            const short8v af_7 = BC8(sA2[(7*4+(KS))*64+lane]);                    \
            PACK2(H00, H01, H10, H11);                                            \
            NEXTPART;                                                             \
            __builtin_amdgcn_s_setprio(1);                                        \
            STEP(0,0); STEP(0,1); STEP(1,0); STEP(1,1);                           \
            STEP(2,0); STEP(2,1); STEP(3,0); STEP(3,1);                           \
            STEP(4,0); STEP(4,1); STEP(5,0); STEP(5,1);                           \
            STEP(6,0); STEP(6,1); STEP(7,0); STEP(7,1);                           \
            __builtin_amdgcn_s_setprio(0);                                        \
            SCHED_FENCE();                                                        \
        }

        KSBLOCK(0, p00, p01, p10, p11,
                a1P_0 = BC8(sA1[4 * 64 + lane]); a1P_1 = BC8(sA1[5 * 64 + lane]);
                L1CALC(a1Q_0, a1Q_1, q00, q01, q10, q11))

        // resolve next unit + prefetch its F rows (atomic has ~1 block to land)
        int nextUnit;
        {
            nextUnit = nStatic + (int)__builtin_amdgcn_readfirstlane((int)nd);
            fv = z4;
            if (lane < 32 && nextUnit < nUnits) {
                int nn2 = nextUnit * UROWS + lane;
                if (nn2 < N) fv = ((const f32x4*)F)[nn2];
            }
        }

        KSBLOCK(1, q00, q01, q10, q11,
                a1Q_0 = BC8(sA1[6 * 64 + lane]); a1Q_1 = BC8(sA1[7 * 64 + lane]);
                L1CALC(a1P_0, a1P_1, p00, p01, p10, p11))
        KSBLOCK(2, p00, p01, p10, p11,
                a3f_0 = BC8(sA3[0 * 64 + lane]); a3f_1 = BC8(sA3[1 * 64 + lane]);
                a3f_2 = BC8(sA3[2 * 64 + lane]); a3f_3 = BC8(sA3[3 * 64 + lane]);
                L1CALC(a1Q_0, a1Q_1, q00, q01, q10, q11))
        KSBLOCK(3, q00, q01, q10, q11, )
        #undef KSBLOCK
        #undef STEP
        #undef PACK2
        #undef L1CALC

        // ---- layer 3: {relu | pack | MFMA}; b2 in acc, b3 in C-in ----
        f32x4 accY_0 = b3v, accY_1 = b3v;
        {
            #define L3K(KS2, JA, JB) {                                                \
                const f32x4 ha0 = relu4(acc_##JA##_0);                                \
                const f32x4 hb0 = relu4(acc_##JB##_0);                                \
                const f32x4 ha1 = relu4(acc_##JA##_1);                                \
                const f32x4 hb1 = relu4(acc_##JB##_1);                                \
                uint4v u0, u1;                                                        \
                u0.x = pk2bf(ha0.x, ha0.y); u0.y = pk2bf(ha0.z, ha0.w);               \
                u0.z = pk2bf(hb0.x, hb0.y); u0.w = pk2bf(hb0.z, hb0.w);               \
                u1.x = pk2bf(ha1.x, ha1.y); u1.y = pk2bf(ha1.z, ha1.w);               \
                u1.z = pk2bf(hb1.x, hb1.y); u1.w = pk2bf(hb1.z, hb1.w);               \
                accY_0 = MFMA(a3f_##KS2, BC8(u0), accY_0);                            \
                accY_1 = MFMA(a3f_##KS2, BC8(u1), accY_1);                            \
            }
            L3K(0, 0, 1) L3K(1, 2, 3) L3K(2, 4, 5) L3K(3, 6, 7)
            #undef L3K
        }
        SCHED_FENCE();

        // ---- epilogue: same-wave LDS transpose, lanes 0..31 finish own row ----
        if (lane < 16) {
            sY[wid * 32 +  0 + lr] = accY_0;
            sY[wid * 32 + 16 + lr] = accY_1;
        }
        {
            const f32x4 yv = sY[wid * 32 + (lane & 31)];
            const int nn = nbase + lane;
            if (lane < 32 && nn < N) {
                const float y0 = yv.x, y1 = yv.y, y2 = yv.z, y3 = yv.w;
                const float s01 = 0.5f * (y1 + y2);
                const float P00 = R00 * y0  + R01 * s01;
                const float P01 = R00 * s01 + R01 * y3;
                const float P10 = R10 * y0  + R11 * s01;
                const float P11 = R10 * s01 + R11 * y3;
                f32x4 o;
                o.x = P00 * fa + P01 * fb;   // cauchy = P @ F^T
                o.y = P00 * fc + P01 * fd;
                o.z = P10 * fa + P11 * fb;
                o.w = P10 * fc + P11 * fd;
                ((f32x4*)out)[nn] = o;
            }
        }
        SCHED_FENCE();

        unit = nextUnit;
    }
}

extern "C" void kernel_launch(void* const* d_in, const int* in_sizes, int n_in,
                              void* d_out, int out_size, void* d_ws, size_t ws_size,
                              hipStream_t stream) {
    const float* F  = (const float*)d_in[0];
    const float* W1 = (const float*)d_in[1];
    const float* b1 = (const float*)d_in[2];
    const float* W2 = (const float*)d_in[3];
    const float* b2 = (const float*)d_in[4];
    const float* W3 = (const float*)d_in[5];
    const float* b3 = (const float*)d_in[6];
    float* out = (float*)d_out;
    const int N = in_sizes[0] / 4;

    unsigned int* cnt = (unsigned int*)d_ws;
    hipMemsetAsync(cnt, 0, sizeof(unsigned int), stream);   // reset work counter each launch

    stress_kernel<<<dim3(NBLK), dim3(TPB), 0, stream>>>(F, W1, b1, W2, b2, W3, b3,
                                                        out, cnt, N);
}

// Round 17
// 52.250 us; speedup vs baseline: 7.1516x; 7.1516x over previous
//
#include <hip/hip_runtime.h>
#include <hip/hip_bf16.h>
#include <math.h>

#define HID   128
#define TPB   256      // 4 waves per block, 32 rows per wave -> 128 rows per block-tile
#define TROWS 128
#define NBLK  768      // persistent grid: 3 blocks/CU

typedef __attribute__((ext_vector_type(8))) short        short8v;   // 8 bf16
typedef __attribute__((ext_vector_type(4))) float        f32x4;
typedef __attribute__((ext_vector_type(4))) unsigned int uint4v;

#define MFMA(a, b, c) __builtin_amdgcn_mfma_f32_16x16x32_bf16((a), (b), (c), 0, 0, 0)
#define SCHED_FENCE() __builtin_amdgcn_sched_barrier(0)
#define BC8(x) __builtin_bit_cast(short8v, x)

// Native packed f32->bf16 pair conversion (1 VALU inst).
__device__ __forceinline__ unsigned int pk2bf(float lo, float hi) {
    unsigned int r;
    asm("v_cvt_pk_bf16_f32 %0, %1, %2" : "=v"(r) : "v"(lo), "v"(hi));
    return r;
}
// bf16 round-trip (hi part of hi-lo split).
__device__ __forceinline__ float bfhi(float x) {
    unsigned int r;
    asm("v_cvt_pk_bf16_f32 %0, %1, %2" : "=v"(r) : "v"(0.f), "v"(x));
    return __builtin_bit_cast(float, r);
}
__device__ __forceinline__ f32x4 relu4(f32x4 v) {
    f32x4 r;
    r.x = fmaxf(v.x, 0.f); r.y = fmaxf(v.y, 0.f);
    r.z = fmaxf(v.z, 0.f); r.w = fmaxf(v.w, 0.f);
    return r;
}

__global__ __launch_bounds__(TPB, 2)
void stress_kernel(const float* __restrict__ F,
                   const float* __restrict__ W1, const float* __restrict__ b1,
                   const float* __restrict__ W2, const float* __restrict__ b2,
                   const float* __restrict__ W3, const float* __restrict__ b3,
                   float* __restrict__ out, int N)
{
    // ---- LDS (~46.6 KB -> 3 blocks/CU) ----
    __shared__ uint4v sA2[2048];   // 32 KB  W2^T A-frags, slot k = 4g+(b&3)+16*(2ks+(b>>2))
    __shared__ uint4v sA1[512];    //  8 KB  layer-1 A-frags (hi-lo W1 + b1 slots)
    __shared__ uint4v sA3[256];    //  4 KB  W3^T A-frags
    __shared__ f32x4  sY[TROWS];   //  2 KB  per-wave y transpose
    __shared__ __align__(16) float sb2[HID];

    const int tid  = threadIdx.x;
    const int lane = tid & 63;
    const int wid  = tid >> 6;
    const int g    = lane >> 4;     // lane group 0..3
    const int lr   = lane & 15;

    // ---- one-time staging ----
    for (int e = tid; e < 2048; e += TPB) {
        int l = e & 63, ks = (e >> 6) & 3, jt = e >> 8;
        int gg = l >> 4;
        int j  = (l & 15) + 16 * jt;
        #define K2(B) (4 * gg + ((B) & 3) + 16 * (2 * ks + ((B) >> 2)))
        uint4v v;
        v.x = pk2bf(W2[K2(0) * HID + j], W2[K2(1) * HID + j]);
        v.y = pk2bf(W2[K2(2) * HID + j], W2[K2(3) * HID + j]);
        v.z = pk2bf(W2[K2(4) * HID + j], W2[K2(5) * HID + j]);
        v.w = pk2bf(W2[K2(6) * HID + j], W2[K2(7) * HID + j]);
        #undef K2
        sA2[e] = v;
    }
    // sA1: layer-1 A-frags. A-row j = lr+16jt; k-slot c = 8g+b:
    //   c=0..2: W1 hi ; c=3..5: W1 lo (pairs xh) ; c=6..8: W1 hi (pairs xl)
    //   c=9: b1 ; c=10: b1 lo ; else 0
    for (int e = tid; e < 512; e += TPB) {
        int l = e & 63, jt = e >> 6;
        int gg = l >> 4;
        int j  = (l & 15) + 16 * jt;
        float av[8];
        #pragma unroll
        for (int b = 0; b < 8; ++b) {
            int c = 8 * gg + b;
            float v;
            if      (c < 3)   v = W1[c * HID + j];
            else if (c < 6)   v = W1[(c - 3) * HID + j] - bfhi(W1[(c - 3) * HID + j]);
            else if (c < 9)   v = W1[(c - 6) * HID + j];
            else if (c == 9)  v = b1[j];
            else if (c == 10) v = b1[j] - bfhi(b1[j]);
            else              v = 0.f;
            av[b] = v;
        }
        uint4v v;
        v.x = pk2bf(av[0], av[1]); v.y = pk2bf(av[2], av[3]);
        v.z = pk2bf(av[4], av[5]); v.w = pk2bf(av[6], av[7]);
        sA1[e] = v;
    }
    for (int e = tid; e < 256; e += TPB) {
        int l = e & 63, ks2 = e >> 6;
        int gg = l >> 4, t = l & 15;
        float w[8];
        #pragma unroll
        for (int b = 0; b < 8; ++b) {
            int j = 4 * gg + (b & 3) + 16 * (2 * ks2 + (b >> 2));
            w[b] = (t < 4) ? W3[j * 4 + t] : 0.f;
        }
        uint4v v;
        v.x = pk2bf(w[0], w[1]); v.y = pk2bf(w[2], w[3]);
        v.z = pk2bf(w[4], w[5]); v.w = pk2bf(w[6], w[7]);
        sA3[e] = v;
    }
    for (int i = tid; i < HID; i += TPB) sb2[i] = b2[i];
    __syncthreads();

    const f32x4* pB2 = (const f32x4*)sb2;
    const f32x4  z4  = {0.f, 0.f, 0.f, 0.f};

    // b3 C-in fragment (only g==0 rows are real W3 rows)
    f32x4 b3v = z4;
    if (g == 0) b3v = *(const f32x4*)b3;

    const int nTiles = (N + TROWS - 1) / TROWS;
    const int tile0  = blockIdx.x;

    // prefetch F for the first tile (lanes 0..31 own rows)
    f32x4 fv = z4;
    {
        const int n = tile0 * TROWS + wid * 32 + lane;
        if (lane < 32 && tile0 < nTiles && n < N) fv = ((const f32x4*)F)[n];
    }

    for (int tile = tile0; tile < nTiles; tile += gridDim.x) {
        const int nbase = tile * TROWS + wid * 32;

        // ---- prologue: invariants + polar R via v_rsq ----
        const float fa = fv.x, fb = fv.y, fc = fv.z, fd = fv.w;
        float x0, x1, x2, R00, R01, R10, R11;
        {
            const float J   = fa * fd - fb * fc;
            const float ss  = fa * fa + fb * fb + fc * fc + fd * fd;
            const float sgn = (J >= 0.f) ? 1.f : -1.f;
            const float s   = fmaxf(ss + 2.f * fabsf(J), 1e-30f);
            float inv;
            asm("v_rsq_f32 %0, %1" : "=v"(inv) : "v"(s));
            const float r = s * inv;            // sqrt(s)
            x0 = r - 2.f; x1 = ss - 1.f; x2 = J - 1.f;
            R00 = (fa + sgn * fd) * inv; R01 = (fb - sgn * fc) * inv;
            R10 = (fc - sgn * fb) * inv; R11 = (fd + sgn * fa) * inv;
        }

        // ---- b2 acc-init reads + a1 frags (KS0/KS1) + B1 frags ----
        const f32x4 ba0 = pB2[g +  0], bb0 = pB2[g +  4];
        const f32x4 ba1 = pB2[g +  8], bb1 = pB2[g + 12];
        const f32x4 ba2 = pB2[g + 16], bb2 = pB2[g + 20];
        const f32x4 ba3 = pB2[g + 24], bb3 = pB2[g + 28];
        short8v a1P_0 = BC8(sA1[0 * 64 + lane]), a1P_1 = BC8(sA1[1 * 64 + lane]);
        short8v a1Q_0 = BC8(sA1[2 * 64 + lane]), a1Q_1 = BC8(sA1[3 * 64 + lane]);
        short8v a3f_0, a3f_1, a3f_2, a3f_3;

        short8v b1f_0, b1f_1;
        #define B1BUILD(RT, DST) {                                                 \
            const float bx0 = __shfl(x0, (RT) * 16 + lr, 64);                      \
            const float bx1 = __shfl(x1, (RT) * 16 + lr, 64);                      \
            const float bx2 = __shfl(x2, (RT) * 16 + lr, 64);                      \
            const float xl0 = bx0 - bfhi(bx0);                                     \
            const float xl1 = bx1 - bfhi(bx1);                                     \
            const float xl2 = bx2 - bfhi(bx2);                                     \
            uint4v u;                                                              \
            u.x = (g == 0) ? pk2bf(bx0, bx1) : ((g == 1) ? pk2bf(xl2, 1.f) : 0u);  \
            u.y = (g == 0) ? pk2bf(bx2, bx0) : ((g == 1) ? pk2bf(1.f, 0.f) : 0u);  \
            u.z = (g == 0) ? pk2bf(bx1, bx2) : 0u;                                 \
            u.w = (g == 0) ? pk2bf(xl0, xl1) : 0u;                                 \
            DST = __builtin_bit_cast(short8v, u);                                  \
        }
        B1BUILD(0, b1f_0) B1BUILD(1, b1f_1)
        #undef B1BUILD

        // L1 lookahead seed (KS0) — its latency hides under acc-init + fence
        #define L1CALC(A0, A1, D00, D01, D10, D11)   \
            D00 = MFMA(A0, b1f_0, z4); D01 = MFMA(A0, b1f_1, z4); \
            D10 = MFMA(A1, b1f_0, z4); D11 = MFMA(A1, b1f_1, z4);
        f32x4 p00, p01, p10, p11, q00, q01, q10, q11;
        L1CALC(a1P_0, a1P_1, p00, p01, p10, p11)
        SCHED_FENCE();

        // ---- layer-2 accumulators, C-in = b2 fragment ----
        f32x4 acc_0_0 = ba0, acc_0_1 = ba0, acc_1_0 = bb0, acc_1_1 = bb0,
              acc_2_0 = ba1, acc_2_1 = ba1, acc_3_0 = bb1, acc_3_1 = bb1,
              acc_4_0 = ba2, acc_4_1 = ba2, acc_5_0 = bb2, acc_5_1 = bb2,
              acc_6_0 = ba3, acc_6_1 = ba3, acc_7_0 = bb3, acc_7_1 = bb3;

        short8v bf_0, bf_1;
        #define PACK2(H00, H01, H10, H11) {                                       \
            const f32x4 ra = relu4(H00), rb = relu4(H10);                         \
            const f32x4 rc = relu4(H01), rd = relu4(H11);                         \
            uint4v u0, u1;                                                        \
            u0.x = pk2bf(ra.x, ra.y); u0.y = pk2bf(ra.z, ra.w);                   \
            u0.z = pk2bf(rb.x, rb.y); u0.w = pk2bf(rb.z, rb.w);                   \
            u1.x = pk2bf(rc.x, rc.y); u1.y = pk2bf(rc.z, rc.w);                   \
            u1.z = pk2bf(rd.x, rd.y); u1.w = pk2bf(rd.z, rd.w);                   \
            bf_0 = BC8(u0); bf_1 = BC8(u1);                                       \
        }
        #define STEP(JT, RT) acc_##JT##_##RT = MFMA(af_##JT, bf_##RT, acc_##JT##_##RT)
        // KSBLOCK: {af reads | pack h(KS) | L1(KS+1) | a1/a3f prefetch | 16 L2 MFMA}
        #define KSBLOCK(KS, H00, H01, H10, H11, NEXTPART) {                       \
            const short8v af_0 = BC8(sA2[(0*4+(KS))*64+lane]);                    \
            const short8v af_1 = BC8(sA2[(1*4+(KS))*64+lane]);                    \
            const short8v af_2 = BC8(sA2[(2*4+(KS))*64+lane]);                    \
            const short8v af_3 = BC8(sA2[(3*4+(KS))*64+lane]);                    \
            const short8v af_4 = BC8(sA2[(4*4+(KS))*64+lane]);                    \
            const short8v af_5 = BC8(sA2[(5*4+(KS))*64+lane]);                    \
            const short8v af_6 = BC8(sA2[(6*4+(KS))*64+lane]);                    \
            const short8v af_7 = BC8(sA2[(7*4+(KS))*64+lane]);                    \
            PACK2(H00, H01, H10, H11);                                            \
            NEXTPART;                                                             \
            __builtin_amdgcn_s_setprio(1);                                        \
            STEP(0,0); STEP(0,1); STEP(1,0); STEP(1,1);                           \
            STEP(2,0); STEP(2,1); STEP(3,0); STEP(3,1);                           \
            STEP(4,0); STEP(4,1); STEP(5,0); STEP(5,1);                           \
            STEP(6,0); STEP(6,1); STEP(7,0); STEP(7,1);                           \
            __builtin_amdgcn_s_setprio(0);                                        \
            SCHED_FENCE();                                                        \
        }

        KSBLOCK(0, p00, p01, p10, p11,
                a1P_0 = BC8(sA1[4 * 64 + lane]); a1P_1 = BC8(sA1[5 * 64 + lane]);
                L1CALC(a1Q_0, a1Q_1, q00, q01, q10, q11))

        // next-tile F prefetch rides in its own tiny region
        {
            const int tn = tile + gridDim.x;
            const int nn = tn * TROWS + wid * 32 + lane;
            fv = z4;
            if (lane < 32 && tn < nTiles && nn < N) fv = ((const f32x4*)F)[nn];
        }

        KSBLOCK(1, q00, q01, q10, q11,
                a1Q_0 = BC8(sA1[6 * 64 + lane]); a1Q_1 = BC8(sA1[7 * 64 + lane]);
                L1CALC(a1P_0, a1P_1, p00, p01, p10, p11))
        KSBLOCK(2, p00, p01, p10, p11,
                a3f_0 = BC8(sA3[0 * 64 + lane]); a3f_1 = BC8(sA3[1 * 64 + lane]);
                a3f_2 = BC8(sA3[2 * 64 + lane]); a3f_3 = BC8(sA3[3 * 64 + lane]);
                L1CALC(a1Q_0, a1Q_1, q00, q01, q10, q11))
        KSBLOCK(3, q00, q01, q10, q11, )
        #undef KSBLOCK
        #undef STEP
        #undef PACK2
        #undef L1CALC

        // ---- layer 3: {relu | pack | MFMA}; b2 in acc, b3 in C-in ----
        f32x4 accY_0 = b3v, accY_1 = b3v;
        {
            #define L3K(KS2, JA, JB) {                                                \
                const f32x4 ha0 = relu4(acc_##JA##_0);                                \
                const f32x4 hb0 = relu4(acc_##JB##_0);                                \
                const f32x4 ha1 = relu4(acc_##JA##_1);                                \
                const f32x4 hb1 = relu4(acc_##JB##_1);                                \
                uint4v u0, u1;                                                        \
                u0.x = pk2bf(ha0.x, ha0.y); u0.y = pk2bf(ha0.z, ha0.w);               \
                u0.z = pk2bf(hb0.x, hb0.y); u0.w = pk2bf(hb0.z, hb0.w);               \
                u1.x = pk2bf(ha1.x, ha1.y); u1.y = pk2bf(ha1.z, ha1.w);               \
                u1.z = pk2bf(hb1.x, hb1.y); u1.w = pk2bf(hb1.z, hb1.w);               \
                accY_0 = MFMA(a3f_##KS2, BC8(u0), accY_0);                            \
                accY_1 = MFMA(a3f_##KS2, BC8(u1), accY_1);                            \
            }
            L3K(0, 0, 1) L3K(1, 2, 3) L3K(2, 4, 5) L3K(3, 6, 7)
            #undef L3K
        }
        SCHED_FENCE();

        // ---- epilogue: same-wave LDS transpose, lanes 0..31 finish own row ----
        if (lane < 16) {
            sY[wid * 32 +  0 + lr] = accY_0;
            sY[wid * 32 + 16 + lr] = accY_1;
        }
        {
            const f32x4 yv = sY[wid * 32 + (lane & 31)];
            const int nn = nbase + lane;
            if (lane < 32 && nn < N) {
                const float y0 = yv.x, y1 = yv.y, y2 = yv.z, y3 = yv.w;
                const float s01 = 0.5f * (y1 + y2);
                const float P00 = R00 * y0  + R01 * s01;
                const float P01 = R00 * s01 + R01 * y3;
                const float P10 = R10 * y0  + R11 * s01;
                const float P11 = R10 * s01 + R11 * y3;
                f32x4 o;
                o.x = P00 * fa + P01 * fb;   // cauchy = P @ F^T
                o.y = P00 * fc + P01 * fd;
                o.z = P10 * fa + P11 * fb;
                o.w = P10 * fc + P11 * fd;
                ((f32x4*)out)[nn] = o;
            }
        }
        SCHED_FENCE();
    }
}

extern "C" void kernel_launch(void* const* d_in, const int* in_sizes, int n_in,
                              void* d_out, int out_size, void* d_ws, size_t ws_size,
                              hipStream_t stream) {
    const float* F  = (const float*)d_in[0];
    const float* W1 = (const float*)d_in[1];
    const float* b1 = (const float*)d_in[2];
    const float* W2 = (const float*)d_in[3];
    const float* b2 = (const float*)d_in[4];
    const float* W3 = (const float*)d_in[5];
    const float* b3 = (const float*)d_in[6];
    float* out = (float*)d_out;
    const int N = in_sizes[0] / 4;

    const int nTiles = (N + TROWS - 1) / TROWS;
    int grid = nTiles < NBLK ? nTiles : NBLK;
    stress_kernel<<<dim3(grid), dim3(TPB), 0, stream>>>(F, W1, b1, W2, b2, W3, b3, out, N);
}

// Round 18
// 45.580 us; speedup vs baseline: 8.1982x; 1.1463x over previous
//
#include <hip/hip_runtime.h>
#include <hip/hip_bf16.h>
#include <math.h>

#define HID   128
#define TPB   256      // 4 waves per block, 32 rows per wave -> 128 rows per block-tile
#define TROWS 128
#define NBLK  768      // persistent grid

typedef __attribute__((ext_vector_type(8))) short        short8v;   // 8 bf16
typedef __attribute__((ext_vector_type(4))) float        f32x4;
typedef __attribute__((ext_vector_type(4))) unsigned int uint4v;

#define MFMA(a, b, c) __builtin_amdgcn_mfma_f32_16x16x32_bf16((a), (b), (c), 0, 0, 0)
#define SCHED_FENCE() __builtin_amdgcn_sched_barrier(0)
#define BC8(x) __builtin_bit_cast(short8v, x)

// Native packed f32->bf16 pair conversion (1 VALU inst).
__device__ __forceinline__ unsigned int pk2bf(float lo, float hi) {
    unsigned int r;
    asm("v_cvt_pk_bf16_f32 %0, %1, %2" : "=v"(r) : "v"(lo), "v"(hi));
    return r;
}
// bf16 round-trip (hi part of hi-lo split).
__device__ __forceinline__ float bfhi(float x) {
    unsigned int r;
    asm("v_cvt_pk_bf16_f32 %0, %1, %2" : "=v"(r) : "v"(0.f), "v"(x));
    return __builtin_bit_cast(float, r);
}
// Packed relu on 2 bf16 halves: bf16 bits are sign-monotone as i16, so
// max_i16(x,0) zeroes negative halves exactly (no NaN/inf in this domain).
__device__ __forceinline__ unsigned int pkrelu(unsigned int x) {
    unsigned int r;
    asm("v_pk_max_i16 %0, %1, %2" : "=v"(r) : "v"(x), "v"(0u));
    return r;
}
__device__ __forceinline__ f32x4 relu4(f32x4 v) {
    f32x4 r;
    r.x = fmaxf(v.x, 0.f); r.y = fmaxf(v.y, 0.f);
    r.z = fmaxf(v.z, 0.f); r.w = fmaxf(v.w, 0.f);
    return r;
}

__global__ __launch_bounds__(TPB, 2)
void stress_kernel(const float* __restrict__ F,
                   const float* __restrict__ W1, const float* __restrict__ b1,
                   const float* __restrict__ W2, const float* __restrict__ b2,
                   const float* __restrict__ W3, const float* __restrict__ b3,
                   float* __restrict__ out, int N)
{
    // ---- LDS (~46.6 KB) ----
    __shared__ uint4v sA2[2048];   // 32 KB  W2^T A-frags, slot k = 4g+(b&3)+16*(2ks+(b>>2))
    __shared__ uint4v sA1[512];    //  8 KB  layer-1 A-frags (hi-lo W1 + b1 slots)
    __shared__ uint4v sA3[256];    //  4 KB  W3^T A-frags
    __shared__ f32x4  sY[TROWS];   //  2 KB  per-wave y transpose
    __shared__ __align__(16) float sb2[HID];

    const int tid  = threadIdx.x;
    const int lane = tid & 63;
    const int wid  = tid >> 6;
    const int g    = lane >> 4;     // lane group 0..3
    const int lr   = lane & 15;

    // ---- one-time staging ----
    for (int e = tid; e < 2048; e += TPB) {
        int l = e & 63, ks = (e >> 6) & 3, jt = e >> 8;
        int gg = l >> 4;
        int j  = (l & 15) + 16 * jt;
        #define K2(B) (4 * gg + ((B) & 3) + 16 * (2 * ks + ((B) >> 2)))
        uint4v v;
        v.x = pk2bf(W2[K2(0) * HID + j], W2[K2(1) * HID + j]);
        v.y = pk2bf(W2[K2(2) * HID + j], W2[K2(3) * HID + j]);
        v.z = pk2bf(W2[K2(4) * HID + j], W2[K2(5) * HID + j]);
        v.w = pk2bf(W2[K2(6) * HID + j], W2[K2(7) * HID + j]);
        #undef K2
        sA2[e] = v;
    }
    // sA1: layer-1 A-frags. A-row j = lr+16jt; k-slot c = 8g+b:
    //   c=0..2: W1 hi ; c=3..5: W1 lo (pairs xh) ; c=6..8: W1 hi (pairs xl)
    //   c=9: b1 ; c=10: b1 lo ; else 0
    for (int e = tid; e < 512; e += TPB) {
        int l = e & 63, jt = e >> 6;
        int gg = l >> 4;
        int j  = (l & 15) + 16 * jt;
        float av[8];
        #pragma unroll
        for (int b = 0; b < 8; ++b) {
            int c = 8 * gg + b;
            float v;
            if      (c < 3)   v = W1[c * HID + j];
            else if (c < 6)   v = W1[(c - 3) * HID + j] - bfhi(W1[(c - 3) * HID + j]);
            else if (c < 9)   v = W1[(c - 6) * HID + j];
            else if (c == 9)  v = b1[j];
            else if (c == 10) v = b1[j] - bfhi(b1[j]);
            else              v = 0.f;
            av[b] = v;
        }
        uint4v v;
        v.x = pk2bf(av[0], av[1]); v.y = pk2bf(av[2], av[3]);
        v.z = pk2bf(av[4], av[5]); v.w = pk2bf(av[6], av[7]);
        sA1[e] = v;
    }
    for (int e = tid; e < 256; e += TPB) {
        int l = e & 63, ks2 = e >> 6;
        int gg = l >> 4, t = l & 15;
        float w[8];
        #pragma unroll
        for (int b = 0; b < 8; ++b) {
            int j = 4 * gg + (b & 3) + 16 * (2 * ks2 + (b >> 2));
            w[b] = (t < 4) ? W3[j * 4 + t] : 0.f;
        }
        uint4v v;
        v.x = pk2bf(w[0], w[1]); v.y = pk2bf(w[2], w[3]);
        v.z = pk2bf(w[4], w[5]); v.w = pk2bf(w[6], w[7]);
        sA3[e] = v;
    }
    for (int i = tid; i < HID; i += TPB) sb2[i] = b2[i];
    __syncthreads();

    const f32x4* pB2 = (const f32x4*)sb2;
    const f32x4  z4  = {0.f, 0.f, 0.f, 0.f};

    // b3 C-in fragment (only g==0 rows are real W3 rows)
    f32x4 b3v = z4;
    if (g == 0) b3v = *(const f32x4*)b3;

    const int nTiles = (N + TROWS - 1) / TROWS;
    const int tile0  = blockIdx.x;

    // prefetch F for the first tile (lanes 0..31 own rows)
    f32x4 fv = z4;
    {
        const int n = tile0 * TROWS + wid * 32 + lane;
        if (lane < 32 && tile0 < nTiles && n < N) fv = ((const f32x4*)F)[n];
    }

    for (int tile = tile0; tile < nTiles; tile += gridDim.x) {
        const int nbase = tile * TROWS + wid * 32;

        // ---- prologue: invariants + polar R via v_rsq ----
        const float fa = fv.x, fb = fv.y, fc = fv.z, fd = fv.w;
        float x0, x1, x2, R00, R01, R10, R11;
        {
            const float J   = fa * fd - fb * fc;
            const float ss  = fa * fa + fb * fb + fc * fc + fd * fd;
            const float sgn = (J >= 0.f) ? 1.f : -1.f;
            const float s   = fmaxf(ss + 2.f * fabsf(J), 1e-30f);
            float inv;
            asm("v_rsq_f32 %0, %1" : "=v"(inv) : "v"(s));
            const float r = s * inv;            // sqrt(s)
            x0 = r - 2.f; x1 = ss - 1.f; x2 = J - 1.f;
            R00 = (fa + sgn * fd) * inv; R01 = (fb - sgn * fc) * inv;
            R10 = (fc - sgn * fb) * inv; R11 = (fd + sgn * fa) * inv;
        }

        // ---- b2 acc-init reads + a1 frags (KS0/KS1) + B1 frags ----
        const f32x4 ba0 = pB2[g +  0], bb0 = pB2[g +  4];
        const f32x4 ba1 = pB2[g +  8], bb1 = pB2[g + 12];
        const f32x4 ba2 = pB2[g + 16], bb2 = pB2[g + 20];
        const f32x4 ba3 = pB2[g + 24], bb3 = pB2[g + 28];
        short8v a1P_0 = BC8(sA1[0 * 64 + lane]), a1P_1 = BC8(sA1[1 * 64 + lane]);
        short8v a1Q_0 = BC8(sA1[2 * 64 + lane]), a1Q_1 = BC8(sA1[3 * 64 + lane]);
        short8v a3f_0, a3f_1, a3f_2, a3f_3;

        short8v b1f_0, b1f_1;
        #define B1BUILD(RT, DST) {                                                 \
            const float bx0 = __shfl(x0, (RT) * 16 + lr, 64);                      \
            const float bx1 = __shfl(x1, (RT) * 16 + lr, 64);                      \
            const float bx2 = __shfl(x2, (RT) * 16 + lr, 64);                      \
            const float xl0 = bx0 - bfhi(bx0);                                     \
            const float xl1 = bx1 - bfhi(bx1);                                     \
            const float xl2 = bx2 - bfhi(bx2);                                     \
            uint4v u;                                                              \
            u.x = (g == 0) ? pk2bf(bx0, bx1) : ((g == 1) ? pk2bf(xl2, 1.f) : 0u);  \
            u.y = (g == 0) ? pk2bf(bx2, bx0) : ((g == 1) ? pk2bf(1.f, 0.f) : 0u);  \
            u.z = (g == 0) ? pk2bf(bx1, bx2) : 0u;                                 \
            u.w = (g == 0) ? pk2bf(xl0, xl1) : 0u;                                 \
            DST = __builtin_bit_cast(short8v, u);                                  \
        }
        B1BUILD(0, b1f_0) B1BUILD(1, b1f_1)
        #undef B1BUILD

        // L1 lookahead seed (KS0)
        #define L1CALC(A0, A1, D00, D01, D10, D11)   \
            D00 = MFMA(A0, b1f_0, z4); D01 = MFMA(A0, b1f_1, z4); \
            D10 = MFMA(A1, b1f_0, z4); D11 = MFMA(A1, b1f_1, z4);
        f32x4 p00, p01, p10, p11, q00, q01, q10, q11;
        L1CALC(a1P_0, a1P_1, p00, p01, p10, p11)
        SCHED_FENCE();

        // ---- layer-2 accumulators, C-in = b2 fragment ----
        f32x4 acc_0_0 = ba0, acc_0_1 = ba0, acc_1_0 = bb0, acc_1_1 = bb0,
              acc_2_0 = ba1, acc_2_1 = ba1, acc_3_0 = bb1, acc_3_1 = bb1,
              acc_4_0 = ba2, acc_4_1 = ba2, acc_5_0 = bb2, acc_5_1 = bb2,
              acc_6_0 = ba3, acc_6_1 = ba3, acc_7_0 = bb3, acc_7_1 = bb3;

        short8v bf_0, bf_1;
        // pack raw h, then packed relu (v_pk_max_i16): 16 inst vs 24.
        #define PACK2(H00, H01, H10, H11) {                                       \
            uint4v u0, u1;                                                        \
            u0.x = pkrelu(pk2bf(H00.x, H00.y)); u0.y = pkrelu(pk2bf(H00.z, H00.w)); \
            u0.z = pkrelu(pk2bf(H10.x, H10.y)); u0.w = pkrelu(pk2bf(H10.z, H10.w)); \
            u1.x = pkrelu(pk2bf(H01.x, H01.y)); u1.y = pkrelu(pk2bf(H01.z, H01.w)); \
            u1.z = pkrelu(pk2bf(H11.x, H11.y)); u1.w = pkrelu(pk2bf(H11.z, H11.w)); \
            bf_0 = BC8(u0); bf_1 = BC8(u1);                                       \
        }
        #define STEP(JT, RT) acc_##JT##_##RT = MFMA(af_##JT, bf_##RT, acc_##JT##_##RT)
        #define KSBLOCK(KS, H00, H01, H10, H11, NEXTPART) {                       \
            const short8v af_0 = BC8(sA2[(0*4+(KS))*64+lane]);                    \
            const short8v af_1 = BC8(sA2[(1*4+(KS))*64+lane]);                    \
            const short8v af_2 = BC8(sA2[(2*4+(KS))*64+lane]);                    \
            const short8v af_3 = BC8(sA2[(3*4+(KS))*64+lane]);                    \
            const short8v af_4 = BC8(sA2[(4*4+(KS))*64+lane]);                    \
            const short8v af_5 = BC8(sA2[(5*4+(KS))*64+lane]);                    \
            const short8v af_6 = BC8(sA2[(6*4+(KS))*64+lane]);                    \
            const short8v af_7 = BC8(sA2[(7*4+(KS))*64+lane]);                    \
            PACK2(H00, H01, H10, H11);                                            \
            NEXTPART;                                                             \
            __builtin_amdgcn_s_setprio(1);                                        \
            STEP(0,0); STEP(0,1); STEP(1,0); STEP(1,1);                           \
            STEP(2,0); STEP(2,1); STEP(3,0); STEP(3,1);                           \
            STEP(4,0); STEP(4,1); STEP(5,0); STEP(5,1);                           \
            STEP(6,0); STEP(6,1); STEP(7,0); STEP(7,1);                           \
            __builtin_amdgcn_s_setprio(0);                                        \
            SCHED_FENCE();                                                        \
        }

        KSBLOCK(0, p00, p01, p10, p11,
                a1P_0 = BC8(sA1[4 * 64 + lane]); a1P_1 = BC8(sA1[5 * 64 + lane]);
                L1CALC(a1Q_0, a1Q_1, q00, q01, q10, q11))

        // next-tile F prefetch rides in its own tiny region
        {
            const int tn = tile + gridDim.x;
            const int nn = tn * TROWS + wid * 32 + lane;
            fv = z4;
            if (lane < 32 && tn < nTiles && nn < N) fv = ((const f32x4*)F)[nn];
        }

        KSBLOCK(1, q00, q01, q10, q11,
                a1Q_0 = BC8(sA1[6 * 64 + lane]); a1Q_1 = BC8(sA1[7 * 64 + lane]);
                L1CALC(a1P_0, a1P_1, p00, p01, p10, p11))
        KSBLOCK(2, p00, p01, p10, p11,
                a3f_0 = BC8(sA3[0 * 64 + lane]); a3f_1 = BC8(sA3[1 * 64 + lane]);
                a3f_2 = BC8(sA3[2 * 64 + lane]); a3f_3 = BC8(sA3[3 * 64 + lane]);
                L1CALC(a1Q_0, a1Q_1, q00, q01, q10, q11))
        KSBLOCK(3, q00, q01, q10, q11, )
        #undef KSBLOCK
        #undef STEP
        #undef PACK2
        #undef L1CALC

        // ---- layer 3: two independent 2-MFMA chains (halves dependent tail) ----
        f32x4 accYa_0 = b3v, accYa_1 = b3v, accYb_0 = z4, accYb_1 = z4;
        {
            #define L3K(KS2, JA, JB, Y0, Y1) {                                        \
                uint4v u0, u1;                                                        \
                u0.x = pkrelu(pk2bf(acc_##JA##_0.x, acc_##JA##_0.y));                 \
                u0.y = pkrelu(pk2bf(acc_##JA##_0.z, acc_##JA##_0.w));                 \
                u0.z = pkrelu(pk2bf(acc_##JB##_0.x, acc_##JB##_0.y));                 \
                u0.w = pkrelu(pk2bf(acc_##JB##_0.z, acc_##JB##_0.w));                 \
                u1.x = pkrelu(pk2bf(acc_##JA##_1.x, acc_##JA##_1.y));                 \
                u1.y = pkrelu(pk2bf(acc_##JA##_1.z, acc_##JA##_1.w));                 \
                u1.z = pkrelu(pk2bf(acc_##JB##_1.x, acc_##JB##_1.y));                 \
                u1.w = pkrelu(pk2bf(acc_##JB##_1.z, acc_##JB##_1.w));                 \
                Y0 = MFMA(a3f_##KS2, BC8(u0), Y0);                                    \
                Y1 = MFMA(a3f_##KS2, BC8(u1), Y1);                                    \
            }
            L3K(0, 0, 1, accYa_0, accYa_1) L3K(2, 4, 5, accYb_0, accYb_1)
            L3K(1, 2, 3, accYa_0, accYa_1) L3K(3, 6, 7, accYb_0, accYb_1)
            #undef L3K
        }
        const f32x4 accY_0 = accYa_0 + accYb_0;
        const f32x4 accY_1 = accYa_1 + accYb_1;
        SCHED_FENCE();

        // ---- epilogue: same-wave LDS transpose, lanes 0..31 finish own row ----
        if (lane < 16) {
            sY[wid * 32 +  0 + lr] = accY_0;
            sY[wid * 32 + 16 + lr] = accY_1;
        }
        {
            const f32x4 yv = sY[wid * 32 + (lane & 31)];
            const int nn = nbase + lane;
            if (lane < 32 && nn < N) {
                const float y0 = yv.x, y1 = yv.y, y2 = yv.z, y3 = yv.w;
                const float s01 = 0.5f * (y1 + y2);
                const float P00 = R00 * y0  + R01 * s01;
                const float P01 = R00 * s01 + R01 * y3;
                const float P10 = R10 * y0  + R11 * s01;
                const float P11 = R10 * s01 + R11 * y3;
                f32x4 o;
                o.x = P00 * fa + P01 * fb;   // cauchy = P @ F^T
                o.y = P00 * fc + P01 * fd;
                o.z = P10 * fa + P11 * fb;
                o.w = P10 * fc + P11 * fd;
                ((f32x4*)out)[nn] = o;
            }
        }
        SCHED_FENCE();
    }
}

extern "C" void kernel_launch(void* const* d_in, const int* in_sizes, int n_in,
                              void* d_out, int out_size, void* d_ws, size_t ws_size,
                              hipStream_t stream) {
    const float* F  = (const float*)d_in[0];
    const float* W1 = (const float*)d_in[1];
    const float* b1 = (const float*)d_in[2];
    const float* W2 = (const float*)d_in[3];
    const float* b2 = (const float*)d_in[4];
    const float* W3 = (const float*)d_in[5];
    const float* b3 = (const float*)d_in[6];
    float* out = (float*)d_out;
    const int N = in_sizes[0] / 4;

    const int nTiles = (N + TROWS - 1) / TROWS;
    int grid = nTiles < NBLK ? nTiles : NBLK;
    stress_kernel<<<dim3(grid), dim3(TPB), 0, stream>>>(F, W1, b1, W2, b2, W3, b3, out, N);
}

// Round 19
// 44.613 us; speedup vs baseline: 8.3757x; 1.0217x over previous
//
#include <hip/hip_runtime.h>
#include <hip/hip_bf16.h>
#include <math.h>

#define HID   128
#define TPB   256      // 4 waves per block, 64 rows per wave -> 256 rows per block-tile
#define TROWS 256
#define NBLK  512      // 2 blocks/CU resident (reg-bucket limited)

typedef __attribute__((ext_vector_type(8))) short        short8v;   // 8 bf16
typedef __attribute__((ext_vector_type(4))) float        f32x4;
typedef __attribute__((ext_vector_type(4))) unsigned int uint4v;

#define MFMA(a, b, c) __builtin_amdgcn_mfma_f32_16x16x32_bf16((a), (b), (c), 0, 0, 0)
#define SCHED_FENCE() __builtin_amdgcn_sched_barrier(0)
#define BC8(x) __builtin_bit_cast(short8v, x)

__device__ __forceinline__ unsigned int pk2bf(float lo, float hi) {
    unsigned int r;
    asm("v_cvt_pk_bf16_f32 %0, %1, %2" : "=v"(r) : "v"(lo), "v"(hi));
    return r;
}
__device__ __forceinline__ float bfhi(float x) {
    unsigned int r;
    asm("v_cvt_pk_bf16_f32 %0, %1, %2" : "=v"(r) : "v"(0.f), "v"(x));
    return __builtin_bit_cast(float, r);
}
// packed relu on 2 bf16 halves (bf16 bits sign-monotone as i16)
__device__ __forceinline__ unsigned int pkrelu(unsigned int x) {
    unsigned int r;
    asm("v_pk_max_i16 %0, %1, %2" : "=v"(r) : "v"(x), "v"(0u));
    return r;
}

__global__ __launch_bounds__(TPB, 2)
void stress_kernel(const float* __restrict__ F,
                   const float* __restrict__ W1, const float* __restrict__ b1,
                   const float* __restrict__ W2, const float* __restrict__ b2,
                   const float* __restrict__ W3, const float* __restrict__ b3,
                   float* __restrict__ out, int N)
{
    // ---- LDS (~48.6 KB) ----
    __shared__ uint4v sA2[2048];   // 32 KB  W2^T A-frags, slot k = 4g+(b&3)+16*(2ks+(b>>2))
    __shared__ uint4v sA1[512];    //  8 KB  layer-1 A-frags (hi-lo W1 + b1 slots)
    __shared__ uint4v sA3[256];    //  4 KB  W3^T A-frags
    __shared__ f32x4  sY[TROWS];   //  4 KB  per-wave y transpose
    __shared__ __align__(16) float sb2[HID];

    const int tid  = threadIdx.x;
    const int lane = tid & 63;
    const int wid  = tid >> 6;
    const int g    = lane >> 4;     // lane group 0..3
    const int lr   = lane & 15;

    // ---- one-time staging (identical maps to R18) ----
    for (int e = tid; e < 2048; e += TPB) {
        int l = e & 63, ks = (e >> 6) & 3, jt = e >> 8;
        int gg = l >> 4;
        int j  = (l & 15) + 16 * jt;
        #define K2(B) (4 * gg + ((B) & 3) + 16 * (2 * ks + ((B) >> 2)))
        uint4v v;
        v.x = pk2bf(W2[K2(0) * HID + j], W2[K2(1) * HID + j]);
        v.y = pk2bf(W2[K2(2) * HID + j], W2[K2(3) * HID + j]);
        v.z = pk2bf(W2[K2(4) * HID + j], W2[K2(5) * HID + j]);
        v.w = pk2bf(W2[K2(6) * HID + j], W2[K2(7) * HID + j]);
        #undef K2
        sA2[e] = v;
    }
    for (int e = tid; e < 512; e += TPB) {
        int l = e & 63, jt = e >> 6;
        int gg = l >> 4;
        int j  = (l & 15) + 16 * jt;
        float av[8];
        #pragma unroll
        for (int b = 0; b < 8; ++b) {
            int c = 8 * gg + b;
            float v;
            if      (c < 3)   v = W1[c * HID + j];
            else if (c < 6)   v = W1[(c - 3) * HID + j] - bfhi(W1[(c - 3) * HID + j]);
            else if (c < 9)   v = W1[(c - 6) * HID + j];
            else if (c == 9)  v = b1[j];
            else if (c == 10) v = b1[j] - bfhi(b1[j]);
            else              v = 0.f;
            av[b] = v;
        }
        uint4v v;
        v.x = pk2bf(av[0], av[1]); v.y = pk2bf(av[2], av[3]);
        v.z = pk2bf(av[4], av[5]); v.w = pk2bf(av[6], av[7]);
        sA1[e] = v;
    }
    for (int e = tid; e < 256; e += TPB) {
        int l = e & 63, ks2 = e >> 6;
        int gg = l >> 4, t = l & 15;
        float w[8];
        #pragma unroll
        for (int b = 0; b < 8; ++b) {
            int j = 4 * gg + (b & 3) + 16 * (2 * ks2 + (b >> 2));
            w[b] = (t < 4) ? W3[j * 4 + t] : 0.f;
        }
        uint4v v;
        v.x = pk2bf(w[0], w[1]); v.y = pk2bf(w[2], w[3]);
        v.z = pk2bf(w[4], w[5]); v.w = pk2bf(w[6], w[7]);
        sA3[e] = v;
    }
    for (int i = tid; i < HID; i += TPB) sb2[i] = b2[i];
    __syncthreads();

    const f32x4* pB2 = (const f32x4*)sb2;
    const f32x4  z4  = {0.f, 0.f, 0.f, 0.f};

    // b3 C-in fragment (only g==0 rows are real W3 rows)
    f32x4 b3v = z4;
    if (g == 0) b3v = *(const f32x4*)b3;

    const int nTiles = (N + TROWS - 1) / TROWS;
    const int tile0  = blockIdx.x;

    // prefetch F for the first tile (all 64 lanes own a row)
    f32x4 fv = z4;
    {
        const int n = tile0 * TROWS + wid * 64 + lane;
        if (tile0 < nTiles && n < N) fv = ((const f32x4*)F)[n];
    }

    for (int tile = tile0; tile < nTiles; tile += gridDim.x) {
        const int nbase = tile * TROWS + wid * 64;

        // ---- prologue (all lanes): invariants + polar R via v_rsq ----
        const float fa = fv.x, fb = fv.y, fc = fv.z, fd = fv.w;
        float x0, x1, x2, R00, R01, R10, R11;
        {
            const float J   = fa * fd - fb * fc;
            const float ss  = fa * fa + fb * fb + fc * fc + fd * fd;
            const float sgn = (J >= 0.f) ? 1.f : -1.f;
            const float s   = fmaxf(ss + 2.f * fabsf(J), 1e-30f);
            float inv;
            asm("v_rsq_f32 %0, %1" : "=v"(inv) : "v"(s));
            const float r = s * inv;
            x0 = r - 2.f; x1 = ss - 1.f; x2 = J - 1.f;
            R00 = (fa + sgn * fd) * inv; R01 = (fb - sgn * fc) * inv;
            R10 = (fc - sgn * fb) * inv; R11 = (fd + sgn * fa) * inv;
        }

        // ---- layer-1 B-frags for 4 row-tiles ----
        short8v b1f_0, b1f_1, b1f_2, b1f_3;
        #define B1BUILD(RT, DST) {                                                 \
            const float bx0 = __shfl(x0, (RT) * 16 + lr, 64);                      \
            const float bx1 = __shfl(x1, (RT) * 16 + lr, 64);                      \
            const float bx2 = __shfl(x2, (RT) * 16 + lr, 64);                      \
            const float xl0 = bx0 - bfhi(bx0);                                     \
            const float xl1 = bx1 - bfhi(bx1);                                     \
            const float xl2 = bx2 - bfhi(bx2);                                     \
            uint4v u;                                                              \
            u.x = (g == 0) ? pk2bf(bx0, bx1) : ((g == 1) ? pk2bf(xl2, 1.f) : 0u);  \
            u.y = (g == 0) ? pk2bf(bx2, bx0) : ((g == 1) ? pk2bf(1.f, 0.f) : 0u);  \
            u.z = (g == 0) ? pk2bf(bx1, bx2) : 0u;                                 \
            u.w = (g == 0) ? pk2bf(xl0, xl1) : 0u;                                 \
            DST = __builtin_bit_cast(short8v, u);                                  \
        }
        B1BUILD(0, b1f_0) B1BUILD(1, b1f_1) B1BUILD(2, b1f_2) B1BUILD(3, b1f_3)
        #undef B1BUILD
        SCHED_FENCE();

        // ---- layer-2 accumulators: 8 jt x 4 rt (128 AGPR), C-in = b2 frag ----
        const f32x4 ba0 = pB2[g +  0], bb0 = pB2[g +  4];
        const f32x4 ba1 = pB2[g +  8], bb1 = pB2[g + 12];
        const f32x4 ba2 = pB2[g + 16], bb2 = pB2[g + 20];
        const f32x4 ba3 = pB2[g + 24], bb3 = pB2[g + 28];
        f32x4 acc_0_0 = ba0, acc_0_1 = ba0, acc_0_2 = ba0, acc_0_3 = ba0;
        f32x4 acc_1_0 = bb0, acc_1_1 = bb0, acc_1_2 = bb0, acc_1_3 = bb0;
        f32x4 acc_2_0 = ba1, acc_2_1 = ba1, acc_2_2 = ba1, acc_2_3 = ba1;
        f32x4 acc_3_0 = bb1, acc_3_1 = bb1, acc_3_2 = bb1, acc_3_3 = bb1;
        f32x4 acc_4_0 = ba2, acc_4_1 = ba2, acc_4_2 = ba2, acc_4_3 = ba2;
        f32x4 acc_5_0 = bb2, acc_5_1 = bb2, acc_5_2 = bb2, acc_5_3 = bb2;
        f32x4 acc_6_0 = ba3, acc_6_1 = ba3, acc_6_2 = ba3, acc_6_3 = ba3;
        f32x4 acc_7_0 = bb3, acc_7_1 = bb3, acc_7_2 = bb3, acc_7_3 = bb3;
        SCHED_FENCE();

        // PACK1: one rt's B-frag from its two L1 results (jt=2ks | jt=2ks+1)
        #define PACK1(PA, PB, BF) {                                               \
            uint4v u;                                                             \
            u.x = pkrelu(pk2bf(PA.x, PA.y)); u.y = pkrelu(pk2bf(PA.z, PA.w));     \
            u.z = pkrelu(pk2bf(PB.x, PB.y)); u.w = pkrelu(pk2bf(PB.z, PB.w));     \
            BF = BC8(u);                                                          \
        }
        #define STEP8(RT, BF)                                                     \
            acc_0_##RT = MFMA(af_0, BF, acc_0_##RT);                              \
            acc_1_##RT = MFMA(af_1, BF, acc_1_##RT);                              \
            acc_2_##RT = MFMA(af_2, BF, acc_2_##RT);                              \
            acc_3_##RT = MFMA(af_3, BF, acc_3_##RT);                              \
            acc_4_##RT = MFMA(af_4, BF, acc_4_##RT);                              \
            acc_5_##RT = MFMA(af_5, BF, acc_5_##RT);                              \
            acc_6_##RT = MFMA(af_6, BF, acc_6_##RT);                              \
            acc_7_##RT = MFMA(af_7, BF, acc_7_##RT);

        // KS block: 5 fence-bounded sub-regions cap live ranges (<=2 L1 pairs)
        #define KSBLOCK(KS) {                                                     \
            const short8v a1_0 = BC8(sA1[(2*(KS)  )*64+lane]);                    \
            const short8v a1_1 = BC8(sA1[(2*(KS)+1)*64+lane]);                    \
            const short8v af_0 = BC8(sA2[(0*4+(KS))*64+lane]);                    \
            const short8v af_1 = BC8(sA2[(1*4+(KS))*64+lane]);                    \
            const short8v af_2 = BC8(sA2[(2*4+(KS))*64+lane]);                    \
            const short8v af_3 = BC8(sA2[(3*4+(KS))*64+lane]);                    \
            const short8v af_4 = BC8(sA2[(4*4+(KS))*64+lane]);                    \
            const short8v af_5 = BC8(sA2[(5*4+(KS))*64+lane]);                    \
            const short8v af_6 = BC8(sA2[(6*4+(KS))*64+lane]);                    \
            const short8v af_7 = BC8(sA2[(7*4+(KS))*64+lane]);                    \
            f32x4 pA0, pB0, pA1, pB1, pA2, pB2_, pA3, pB3;                        \
            pA0 = MFMA(a1_0, b1f_0, z4); pB0 = MFMA(a1_1, b1f_0, z4);             \
            pA1 = MFMA(a1_0, b1f_1, z4); pB1 = MFMA(a1_1, b1f_1, z4);             \
            SCHED_FENCE();                                                        \
            {                                                                     \
                short8v bf;                                                       \
                PACK1(pA0, pB0, bf);                                              \
                pA2 = MFMA(a1_0, b1f_2, z4); pB2_ = MFMA(a1_1, b1f_2, z4);        \
                __builtin_amdgcn_s_setprio(1); STEP8(0, bf)                       \
                __builtin_amdgcn_s_setprio(0);                                    \
            }                                                                     \
            SCHED_FENCE();                                                        \
            {                                                                     \
                short8v bf;                                                       \
                PACK1(pA1, pB1, bf);                                              \
                pA3 = MFMA(a1_0, b1f_3, z4); pB3 = MFMA(a1_1, b1f_3, z4);         \
                __builtin_amdgcn_s_setprio(1); STEP8(1, bf)                       \
                __builtin_amdgcn_s_setprio(0);                                    \
            }                                                                     \
            SCHED_FENCE();                                                        \
            {                                                                     \
                short8v bf;                                                       \
                PACK1(pA2, pB2_, bf);                                             \
                __builtin_amdgcn_s_setprio(1); STEP8(2, bf)                       \
                __builtin_amdgcn_s_setprio(0);                                    \
            }                                                                     \
            SCHED_FENCE();                                                        \
            {                                                                     \
                short8v bf;                                                       \
                PACK1(pA3, pB3, bf);                                              \
                __builtin_amdgcn_s_setprio(1); STEP8(3, bf)                       \
                __builtin_amdgcn_s_setprio(0);                                    \
            }                                                                     \
            SCHED_FENCE();                                                        \
        }

        KSBLOCK(0)
        // next-tile F prefetch in its own tiny region
        {
            const int tn = tile + gridDim.x;
            const int nn = tn * TROWS + wid * 64 + lane;
            fv = z4;
            if (tn < nTiles && nn < N) fv = ((const f32x4*)F)[nn];
        }
        KSBLOCK(1)
        KSBLOCK(2)
        KSBLOCK(3)
        #undef KSBLOCK
        #undef STEP8

        // ---- layer 3: per-KS2 fenced regions; b2 in acc, b3 in C-in ----
        f32x4 accY_0 = b3v, accY_1 = b3v, accY_2 = b3v, accY_3 = b3v;
        #define L3RT(RT, JA, JB, A3) {                                            \
            uint4v u;                                                             \
            u.x = pkrelu(pk2bf(acc_##JA##_##RT.x, acc_##JA##_##RT.y));            \
            u.y = pkrelu(pk2bf(acc_##JA##_##RT.z, acc_##JA##_##RT.w));            \
            u.z = pkrelu(pk2bf(acc_##JB##_##RT.x, acc_##JB##_##RT.y));            \
            u.w = pkrelu(pk2bf(acc_##JB##_##RT.z, acc_##JB##_##RT.w));            \
            accY_##RT = MFMA(A3, BC8(u), accY_##RT);                              \
        }
        #define L3K(KS2, JA, JB) {                                                \
            const short8v a3f = BC8(sA3[(KS2) * 64 + lane]);                      \
            L3RT(0, JA, JB, a3f) L3RT(1, JA, JB, a3f)                             \
            L3RT(2, JA, JB, a3f) L3RT(3, JA, JB, a3f)                             \
        } SCHED_FENCE();
        L3K(0, 0, 1) L3K(1, 2, 3) L3K(2, 4, 5) L3K(3, 6, 7)
        #undef L3K
        #undef L3RT
        #undef PACK1

        // ---- epilogue: same-wave LDS transpose, every lane finishes own row ----
        if (lane < 16) {
            sY[wid * 64 +  0 + lr] = accY_0;
            sY[wid * 64 + 16 + lr] = accY_1;
            sY[wid * 64 + 32 + lr] = accY_2;
            sY[wid * 64 + 48 + lr] = accY_3;
        }
        {
            const f32x4 yv = sY[wid * 64 + lane];   // same-wave LDS: no barrier
            const int nn = nbase + lane;
            if (nn < N) {
                const float y0 = yv.x, y1 = yv.y, y2 = yv.z, y3 = yv.w;
                const float s01 = 0.5f * (y1 + y2);
                const float P00 = R00 * y0  + R01 * s01;
                const float P01 = R00 * s01 + R01 * y3;
                const float P10 = R10 * y0  + R11 * s01;
                const float P11 = R10 * s01 + R11 * y3;
                f32x4 o;
                o.x = P00 * fa + P01 * fb;   // cauchy = P @ F^T
                o.y = P00 * fc + P01 * fd;
                o.z = P10 * fa + P11 * fb;
                o.w = P10 * fc + P11 * fd;
                ((f32x4*)out)[nn] = o;
            }
        }
        SCHED_FENCE();
    }
}

extern "C" void kernel_launch(void* const* d_in, const int* in_sizes, int n_in,
                              void* d_out, int out_size, void* d_ws, size_t ws_size,
                              hipStream_t stream) {
    const float* F  = (const float*)d_in[0];
    const float* W1 = (const float*)d_in[1];
    const float* b1 = (const float*)d_in[2];
    const float* W2 = (const float*)d_in[3];
    const float* b2 = (const float*)d_in[4];
    const float* W3 = (const float*)d_in[5];
    const float* b3 = (const float*)d_in[6];
    float* out = (float*)d_out;
    const int N = in_sizes[0] / 4;

    const int nTiles = (N + TROWS - 1) / TROWS;
    int grid = nTiles < NBLK ? nTiles : NBLK;
    stress_kernel<<<dim3(grid), dim3(TPB), 0, stream>>>(F, W1, b1, W2, b2, W3, b3, out, N);
}